// Round 13
// baseline (418.831 us; speedup 1.0000x reference)
//
#include <hip/hip_runtime.h>

#define NN   8192
#define DIN  512
#define H1   32
#define H2   16
#define NE   262144
#define EPSV 1e-32f

// ---------------- k1: XW0 = X @ W0  [NN x H1]; also zero-inits hacc & mean ----------------
__global__ __launch_bounds__(256) void k_xw0(const float* __restrict__ X,
                                             const float* __restrict__ W0,
                                             float* __restrict__ XW0,
                                             float* __restrict__ hacc,
                                             float* __restrict__ mean) {
    int t = blockIdx.x * 256 + threadIdx.x;
    hacc[t] = 0.f;
    if (t < NN * H2) mean[t] = 0.f;
    int r = t >> 5, c = t & 31;
    const float4* Xr = reinterpret_cast<const float4*>(X + (size_t)r * DIN);
    float acc = 0.f;
#pragma unroll 8
    for (int k4 = 0; k4 < DIN / 4; ++k4) {
        float4 x = Xr[k4];
        int k = k4 * 4;
        acc = fmaf(x.x, W0[(k + 0) * H1 + c], acc);
        acc = fmaf(x.y, W0[(k + 1) * H1 + c], acc);
        acc = fmaf(x.z, W0[(k + 2) * H1 + c], acc);
        acc = fmaf(x.w, W0[(k + 3) * H1 + c], acc);
    }
    XW0[t] = acc;
}

// ---------------- k2: hacc += scale * edge_val * XW0[col]  (native HW atomic) ----------------
// unsafeAtomicAdd -> global_atomic_add_f32 (no CAS retry loop; denorm-flush
// harmless, all values normal). scale=1 real pass; scale=0 attribution pass
// (adds +-0.0, result unchanged, identical atomic traffic).
#define SPMM_GRID 2048
__global__ __launch_bounds__(256) void k_spmm1(const int* __restrict__ er,
                                               const int* __restrict__ ec,
                                               const float* __restrict__ ev,
                                               const float* __restrict__ XW0,
                                               float* __restrict__ hacc,
                                               float scale) {
    const int stride = SPMM_GRID * 256;
    for (int idx = blockIdx.x * 256 + threadIdx.x; idx < NE * H1; idx += stride) {
        int e = idx >> 5, c = idx & 31;
        unsafeAtomicAdd(&hacc[er[e] * H1 + c], scale * ev[e] * XW0[ec[e] * H1 + c]);
    }
}

// ---------------- k3: HW1 = relu(hacc) @ W1   [NN x H2] ----------------
__global__ __launch_bounds__(256) void k_hw1(const float* __restrict__ hacc,
                                             const float* __restrict__ W1,
                                             float* __restrict__ HW1) {
    int t = blockIdx.x * 256 + threadIdx.x;
    int r = t >> 4, c = t & 15;
    const float4* hr = reinterpret_cast<const float4*>(hacc + r * H1);
    float acc = 0.f;
#pragma unroll
    for (int k4 = 0; k4 < H1 / 4; ++k4) {
        float4 h = hr[k4];
        int k = k4 * 4;
        acc = fmaf(fmaxf(h.x, 0.f), W1[(k + 0) * H2 + c], acc);
        acc = fmaf(fmaxf(h.y, 0.f), W1[(k + 1) * H2 + c], acc);
        acc = fmaf(fmaxf(h.z, 0.f), W1[(k + 2) * H2 + c], acc);
        acc = fmaf(fmaxf(h.w, 0.f), W1[(k + 3) * H2 + c], acc);
    }
    HW1[t] = acc;
}

// ---------------- k4: mean += scale * edge_val * HW1[col]  (native HW atomic) ----------------
__global__ __launch_bounds__(256) void k_spmm2(const int* __restrict__ er,
                                               const int* __restrict__ ec,
                                               const float* __restrict__ ev,
                                               const float* __restrict__ HW1,
                                               float* __restrict__ mean,
                                               float scale) {
    const int stride = SPMM_GRID * 256;
    for (int idx = blockIdx.x * 256 + threadIdx.x; idx < NE * H2; idx += stride) {
        int e = idx >> 4, c = idx & 15;
        unsafeAtomicAdd(&mean[er[e] * H2 + c], scale * ev[e] * HW1[ec[e] * H2 + c]);
    }
}

// ---------------- k5: out = sigmoid(Z @ Z^T), Z = max(mean, EPS) ----------------
// (byte-identical to round 6; measured at its 42 us write floor in R11)
#define TI 128

__device__ __forceinline__ float sigm(float x) {
    return __fdividef(1.0f, 1.0f + __expf(-x));
}

__global__ __launch_bounds__(256) void k_decode(const float* __restrict__ Zm,
                                                float* __restrict__ out) {
    __shared__ float zi[TI * 16];    // pitch 16, granule-XOR
    __shared__ float zj[TI * 32];    // pitch 32, 8-slot XOR placement
    const int i0 = blockIdx.y * TI, j0 = blockIdx.x * TI;
    const int tid = threadIdx.x;

#pragma unroll
    for (int l = 0; l < 2; ++l) {
        int t = tid + l * 256;          // 0..511
        int r = t >> 2, q = t & 3;      // row, float4-granule
        float4 a = *reinterpret_cast<const float4*>(Zm + (size_t)(i0 + r) * H2 + q * 4);
        float4 b = *reinterpret_cast<const float4*>(Zm + (size_t)(j0 + r) * H2 + q * 4);
        a.x = fmaxf(a.x, EPSV); a.y = fmaxf(a.y, EPSV);
        a.z = fmaxf(a.z, EPSV); a.w = fmaxf(a.w, EPSV);
        b.x = fmaxf(b.x, EPSV); b.y = fmaxf(b.y, EPSV);
        b.z = fmaxf(b.z, EPSV); b.w = fmaxf(b.w, EPSV);
        int g  = (r >> 3);              // 0..15
        int qs = q ^ (g & 3);                       // zi granule swizzle
        int p  = (q ^ (g & 3)) | (g & 4);           // zj slot placement
        *reinterpret_cast<float4*>(&zi[r * 16 + qs * 4]) = a;
        *reinterpret_cast<float4*>(&zj[r * 32 + p  * 4]) = b;
    }
    __syncthreads();

    const int tx = tid & 15, ty = tid >> 4;
    float acc[8][8] = {};
#pragma unroll
    for (int k4 = 0; k4 < 4; ++k4) {
        float4 ra[8], rb[8];
        const int qi = (k4 ^ (ty & 3)) * 4;              // zi un-swizzle (r>>3 == ty)
        const int pj = ((k4 ^ (tx & 3)) | (tx & 4)) * 4; // zj slot (r>>3 == tx)
#pragma unroll
        for (int a = 0; a < 8; ++a)
            ra[a] = *reinterpret_cast<const float4*>(&zi[(ty * 8 + a) * 16 + qi]);
#pragma unroll
        for (int b = 0; b < 8; ++b)
            rb[b] = *reinterpret_cast<const float4*>(&zj[(tx * 8 + b) * 32 + pj]);
#pragma unroll
        for (int a = 0; a < 8; ++a)
#pragma unroll
            for (int b = 0; b < 8; ++b) {
                acc[a][b] = fmaf(ra[a].x, rb[b].x, acc[a][b]);
                acc[a][b] = fmaf(ra[a].y, rb[b].y, acc[a][b]);
                acc[a][b] = fmaf(ra[a].z, rb[b].z, acc[a][b]);
                acc[a][b] = fmaf(ra[a].w, rb[b].w, acc[a][b]);
            }
    }

#pragma unroll
    for (int a = 0; a < 8; ++a) {
        size_t rowbase = (size_t)(i0 + ty * 8 + a) * NN + j0 + tx * 8;
#pragma unroll
        for (int b4 = 0; b4 < 8; b4 += 4) {
            float4 o;
            o.x = sigm(acc[a][b4 + 0]);
            o.y = sigm(acc[a][b4 + 1]);
            o.z = sigm(acc[a][b4 + 2]);
            o.w = sigm(acc[a][b4 + 3]);
            *reinterpret_cast<float4*>(out + rowbase + b4) = o;
        }
    }
}

extern "C" void kernel_launch(void* const* d_in, const int* in_sizes, int n_in,
                              void* d_out, int out_size, void* d_ws, size_t ws_size,
                              hipStream_t stream) {
    const float* X  = (const float*)d_in[0];
    const int*   er = (const int*)d_in[1];
    const int*   ec = (const int*)d_in[2];
    const float* ev = (const float*)d_in[3];
    const float* W0 = (const float*)d_in[4];
    const float* W1 = (const float*)d_in[5];
    // d_in[6] = W2: dead in eval path.
    float* out = (float*)d_out;

    char* ws = (char*)d_ws;
    float* XW0  = (float*)(ws);                          // 1 MB
    float* hacc = (float*)(ws + (1 << 20));              // 1 MB
    float* mean = (float*)(ws + (2 << 20));              // 512 KB
    float* HW1  = (float*)(ws + (2 << 20) + (512 << 10));// 512 KB

    k_xw0   <<<NN * H1 / 256, 256, 0, stream>>>(X, W0, XW0, hacc, mean);
    k_spmm1 <<<SPMM_GRID, 256, 0, stream>>>(er, ec, ev, XW0, hacc, 1.0f);
    k_hw1   <<<NN * H2 / 256, 256, 0, stream>>>(hacc, W1, HW1);
    k_spmm2 <<<SPMM_GRID, 256, 0, stream>>>(er, ec, ev, HW1, mean, 1.0f);
    // ---- attribution duplicates: scale=0 adds +-0.0 (result unchanged),
    // identical atomic traffic -> dur delta == T_spmm1 + T_spmm2 ----
    k_spmm1 <<<SPMM_GRID, 256, 0, stream>>>(er, ec, ev, XW0, hacc, 0.0f);
    k_spmm2 <<<SPMM_GRID, 256, 0, stream>>>(er, ec, ev, HW1, mean, 0.0f);
    k_decode<<<dim3(NN / TI, NN / TI), 256, 0, stream>>>(mean, out);
}

// Round 14
// 374.027 us; speedup vs baseline: 1.1198x; 1.1198x over previous
//
#include <hip/hip_runtime.h>

#define NN   8192
#define DIN  512
#define H1   32
#define H2   16
#define NE   262144
#define EPSV 1e-32f

// ---------------- k1: XW0 = X @ W0  [NN x H1]; also zero-inits hacc & mean ----------------
__global__ __launch_bounds__(256) void k_xw0(const float* __restrict__ X,
                                             const float* __restrict__ W0,
                                             float* __restrict__ XW0,
                                             float* __restrict__ hacc,
                                             float* __restrict__ mean) {
    int t = blockIdx.x * 256 + threadIdx.x;
    hacc[t] = 0.f;
    if (t < NN * H2) mean[t] = 0.f;
    int r = t >> 5, c = t & 31;
    const float4* Xr = reinterpret_cast<const float4*>(X + (size_t)r * DIN);
    float acc = 0.f;
#pragma unroll 8
    for (int k4 = 0; k4 < DIN / 4; ++k4) {
        float4 x = Xr[k4];
        int k = k4 * 4;
        acc = fmaf(x.x, W0[(k + 0) * H1 + c], acc);
        acc = fmaf(x.y, W0[(k + 1) * H1 + c], acc);
        acc = fmaf(x.z, W0[(k + 2) * H1 + c], acc);
        acc = fmaf(x.w, W0[(k + 3) * H1 + c], acc);
    }
    XW0[t] = acc;
}

// ---------------- k2: hacc += edge_val * XW0[col]  (native HW atomic) ----------------
// Measured (R13 attribution): SPMM pair = 44 us ~ atomic-throughput floor;
// beats CSR+gather (53), replication (+9), CAS (equal). Grid-stride per G11.
#define SPMM_GRID 2048
__global__ __launch_bounds__(256) void k_spmm1(const int* __restrict__ er,
                                               const int* __restrict__ ec,
                                               const float* __restrict__ ev,
                                               const float* __restrict__ XW0,
                                               float* __restrict__ hacc) {
    const int stride = SPMM_GRID * 256;
    for (int idx = blockIdx.x * 256 + threadIdx.x; idx < NE * H1; idx += stride) {
        int e = idx >> 5, c = idx & 31;
        unsafeAtomicAdd(&hacc[er[e] * H1 + c], ev[e] * XW0[ec[e] * H1 + c]);
    }
}

// ---------------- k3: HW1 = relu(hacc) @ W1   [NN x H2] ----------------
__global__ __launch_bounds__(256) void k_hw1(const float* __restrict__ hacc,
                                             const float* __restrict__ W1,
                                             float* __restrict__ HW1) {
    int t = blockIdx.x * 256 + threadIdx.x;
    int r = t >> 4, c = t & 15;
    const float4* hr = reinterpret_cast<const float4*>(hacc + r * H1);
    float acc = 0.f;
#pragma unroll
    for (int k4 = 0; k4 < H1 / 4; ++k4) {
        float4 h = hr[k4];
        int k = k4 * 4;
        acc = fmaf(fmaxf(h.x, 0.f), W1[(k + 0) * H2 + c], acc);
        acc = fmaf(fmaxf(h.y, 0.f), W1[(k + 1) * H2 + c], acc);
        acc = fmaf(fmaxf(h.z, 0.f), W1[(k + 2) * H2 + c], acc);
        acc = fmaf(fmaxf(h.w, 0.f), W1[(k + 3) * H2 + c], acc);
    }
    HW1[t] = acc;
}

// ---------------- k4: mean += edge_val * HW1[col]  (native HW atomic) ----------------
__global__ __launch_bounds__(256) void k_spmm2(const int* __restrict__ er,
                                               const int* __restrict__ ec,
                                               const float* __restrict__ ev,
                                               const float* __restrict__ HW1,
                                               float* __restrict__ mean) {
    const int stride = SPMM_GRID * 256;
    for (int idx = blockIdx.x * 256 + threadIdx.x; idx < NE * H2; idx += stride) {
        int e = idx >> 4, c = idx & 15;
        unsafeAtomicAdd(&mean[er[e] * H2 + c], ev[e] * HW1[ec[e] * H2 + c]);
    }
}

// ---------------- k5: out = sigmoid(Z @ Z^T), Z = max(mean, EPS) ----------------
// Measured 42 us standalone (R11 attribution) = 256 MB @ 6.2 TB/s write floor.
// Conflict-free LDS (zi granule-XOR broadcast reads; zj 8-slot XOR placement,
// <=2-way on reads) + contiguous float4 stores (R5 showed NT-scalar regresses).
#define TI 128

__device__ __forceinline__ float sigm(float x) {
    return __fdividef(1.0f, 1.0f + __expf(-x));
}

__global__ __launch_bounds__(256) void k_decode(const float* __restrict__ Zm,
                                                float* __restrict__ out) {
    __shared__ float zi[TI * 16];    // pitch 16, granule-XOR
    __shared__ float zj[TI * 32];    // pitch 32, 8-slot XOR placement
    const int i0 = blockIdx.y * TI, j0 = blockIdx.x * TI;
    const int tid = threadIdx.x;

#pragma unroll
    for (int l = 0; l < 2; ++l) {
        int t = tid + l * 256;          // 0..511
        int r = t >> 2, q = t & 3;      // row, float4-granule
        float4 a = *reinterpret_cast<const float4*>(Zm + (size_t)(i0 + r) * H2 + q * 4);
        float4 b = *reinterpret_cast<const float4*>(Zm + (size_t)(j0 + r) * H2 + q * 4);
        a.x = fmaxf(a.x, EPSV); a.y = fmaxf(a.y, EPSV);
        a.z = fmaxf(a.z, EPSV); a.w = fmaxf(a.w, EPSV);
        b.x = fmaxf(b.x, EPSV); b.y = fmaxf(b.y, EPSV);
        b.z = fmaxf(b.z, EPSV); b.w = fmaxf(b.w, EPSV);
        int g  = (r >> 3);              // 0..15
        int qs = q ^ (g & 3);                       // zi granule swizzle
        int p  = (q ^ (g & 3)) | (g & 4);           // zj slot placement
        *reinterpret_cast<float4*>(&zi[r * 16 + qs * 4]) = a;
        *reinterpret_cast<float4*>(&zj[r * 32 + p  * 4]) = b;
    }
    __syncthreads();

    const int tx = tid & 15, ty = tid >> 4;
    float acc[8][8] = {};
#pragma unroll
    for (int k4 = 0; k4 < 4; ++k4) {
        float4 ra[8], rb[8];
        const int qi = (k4 ^ (ty & 3)) * 4;              // zi un-swizzle (r>>3 == ty)
        const int pj = ((k4 ^ (tx & 3)) | (tx & 4)) * 4; // zj slot (r>>3 == tx)
#pragma unroll
        for (int a = 0; a < 8; ++a)
            ra[a] = *reinterpret_cast<const float4*>(&zi[(ty * 8 + a) * 16 + qi]);
#pragma unroll
        for (int b = 0; b < 8; ++b)
            rb[b] = *reinterpret_cast<const float4*>(&zj[(tx * 8 + b) * 32 + pj]);
#pragma unroll
        for (int a = 0; a < 8; ++a)
#pragma unroll
            for (int b = 0; b < 8; ++b) {
                acc[a][b] = fmaf(ra[a].x, rb[b].x, acc[a][b]);
                acc[a][b] = fmaf(ra[a].y, rb[b].y, acc[a][b]);
                acc[a][b] = fmaf(ra[a].z, rb[b].z, acc[a][b]);
                acc[a][b] = fmaf(ra[a].w, rb[b].w, acc[a][b]);
            }
    }

#pragma unroll
    for (int a = 0; a < 8; ++a) {
        size_t rowbase = (size_t)(i0 + ty * 8 + a) * NN + j0 + tx * 8;
#pragma unroll
        for (int b4 = 0; b4 < 8; b4 += 4) {
            float4 o;
            o.x = sigm(acc[a][b4 + 0]);
            o.y = sigm(acc[a][b4 + 1]);
            o.z = sigm(acc[a][b4 + 2]);
            o.w = sigm(acc[a][b4 + 3]);
            *reinterpret_cast<float4*>(out + rowbase + b4) = o;
        }
    }
}

extern "C" void kernel_launch(void* const* d_in, const int* in_sizes, int n_in,
                              void* d_out, int out_size, void* d_ws, size_t ws_size,
                              hipStream_t stream) {
    const float* X  = (const float*)d_in[0];
    const int*   er = (const int*)d_in[1];
    const int*   ec = (const int*)d_in[2];
    const float* ev = (const float*)d_in[3];
    const float* W0 = (const float*)d_in[4];
    const float* W1 = (const float*)d_in[5];
    // d_in[6] = W2: dead in eval path (std unused when Z = mean).
    float* out = (float*)d_out;

    char* ws = (char*)d_ws;
    float* XW0  = (float*)(ws);                          // 1 MB
    float* hacc = (float*)(ws + (1 << 20));              // 1 MB
    float* mean = (float*)(ws + (2 << 20));              // 512 KB
    float* HW1  = (float*)(ws + (2 << 20) + (512 << 10));// 512 KB

    k_xw0   <<<NN * H1 / 256, 256, 0, stream>>>(X, W0, XW0, hacc, mean);
    k_spmm1 <<<SPMM_GRID, 256, 0, stream>>>(er, ec, ev, XW0, hacc);
    k_hw1   <<<NN * H2 / 256, 256, 0, stream>>>(hacc, W1, HW1);
    k_spmm2 <<<SPMM_GRID, 256, 0, stream>>>(er, ec, ev, HW1, mean);
    k_decode<<<dim3(NN / TI, NN / TI), 256, 0, stream>>>(mean, out);
}